// Round 1
// baseline (614.780 us; speedup 1.0000x reference)
//
#include <hip/hip_runtime.h>

// ---------------------------------------------------------------------------
// MultiViewGraphAttention: 2-layer GAT (H=4 heads, HID=64), fused epilogues.
// Pipeline per call:
//   CSR build (deg -> scan -> scatter)           [int scratch]
//   H1 = x@W1 [N,256]; RES = x@W_in+b_in [N,64]
//   eS/eD[n,h] = <H1[n,h,:], a_src/dst[h,:]>
//   agg1: per-dst softmax + aggregate + mean-heads + b1 + ELU + RES + LN -> HL1
//   H2 = HL1@W2; eS/eD from H2
//   agg2: ... + HL1 residual + LN -> HL2
//   OUT = HL2@Wo + bo
// Workspace ~83 MB, everything we read is written first (0xAA-poison safe).
// ---------------------------------------------------------------------------

__device__ __forceinline__ float wave_sum(float v) {
#pragma unroll
  for (int m = 32; m >= 1; m >>= 1) v += __shfl_xor(v, m, 64);
  return v;
}

// ---------------- generic small GEMM: C[n][j] = sum_k A[n][k]B[k][j] (+bias)
template <int K, int J, bool BIAS>
__global__ __launch_bounds__(256) void gemm_kernel(
    const float* __restrict__ A, const float* __restrict__ B,
    const float* __restrict__ bias, float* __restrict__ C, int nrows) {
  constexpr int JV = J / 64;  // cols per lane
  __shared__ float As[32 * K];
  const int row0 = blockIdx.x * 32;
  const int tid = threadIdx.x;
  int valid = nrows - row0;
  if (valid > 32) valid = 32;
  // stage A tile (tile is contiguous in row-major A)
  for (int idx = tid * 4; idx < 32 * K; idx += 256 * 4) {
    float4 v = make_float4(0.f, 0.f, 0.f, 0.f);
    if (idx < valid * K) v = *(const float4*)(A + (long)row0 * K + idx);
    *(float4*)(As + idx) = v;
  }
  __syncthreads();
  const int lane = tid & 63;
  const int wid = tid >> 6;  // 4 waves x 8 rows
  float acc[8][JV];
#pragma unroll
  for (int r = 0; r < 8; ++r)
#pragma unroll
    for (int v = 0; v < JV; ++v) acc[r][v] = 0.f;
  const float* Bp = B + lane;
#pragma unroll 4
  for (int k = 0; k < K; ++k) {
    float bv[JV];
#pragma unroll
    for (int v = 0; v < JV; ++v) bv[v] = Bp[k * J + v * 64];
#pragma unroll
    for (int r = 0; r < 8; ++r) {
      float a = As[(wid * 8 + r) * K + k];  // LDS broadcast within wave
#pragma unroll
      for (int v = 0; v < JV; ++v) acc[r][v] = fmaf(a, bv[v], acc[r][v]);
    }
  }
#pragma unroll
  for (int r = 0; r < 8; ++r) {
    int row = row0 + wid * 8 + r;
    if (row < nrows) {
#pragma unroll
      for (int v = 0; v < JV; ++v) {
        int j = lane + v * 64;
        float o = acc[r][v];
        if (BIAS) o += bias[j];
        C[(long)row * J + j] = o;
      }
    }
  }
}

// --------------- attention logits: eS[n][h]=<H[n,h,:],a_src[h,:]>, eD likewise
__global__ __launch_bounds__(256) void attpre_kernel(
    const float* __restrict__ H, const float* __restrict__ a_src,
    const float* __restrict__ a_dst, float* __restrict__ eS,
    float* __restrict__ eD, int n) {
  const int lane = threadIdx.x & 63;
  const int node = blockIdx.x * 4 + (threadIdx.x >> 6);
  if (node >= n) return;
  const int h = lane >> 4;   // head 0..3
  const int q = lane & 15;   // 16 lanes per head, 4 ch each
  const float4 hv = *(const float4*)(H + (long)node * 256 + h * 64 + q * 4);
  const float4 as = *(const float4*)(a_src + h * 64 + q * 4);
  const float4 ad = *(const float4*)(a_dst + h * 64 + q * 4);
  float ps = hv.x * as.x + hv.y * as.y + hv.z * as.z + hv.w * as.w;
  float pd = hv.x * ad.x + hv.y * ad.y + hv.z * ad.z + hv.w * ad.w;
#pragma unroll
  for (int m = 8; m >= 1; m >>= 1) {
    ps += __shfl_xor(ps, m, 64);
    pd += __shfl_xor(pd, m, 64);
  }
  if (q == 0) {
    eS[node * 4 + h] = ps;
    eD[node * 4 + h] = pd;
  }
}

// ---------------- CSR build ----------------
__global__ void initdeg_kernel(int* deg, int n) {
  int i = blockIdx.x * 256 + threadIdx.x;
  if (i < n) deg[i] = 1;  // self-loop
}
__global__ void count_kernel(const int* __restrict__ dst, int* deg, int E) {
  int e = blockIdx.x * 256 + threadIdx.x;
  if (e < E) atomicAdd(&deg[dst[e]], 1);
}
// single-block scan: reads deg(==cursor), writes rowptr[0..n] and cursor=start
__global__ __launch_bounds__(1024) void scan_kernel(int* cursor, int* rowptr, int n) {
  __shared__ int smem[1024];
  __shared__ int carry;
  const int tid = threadIdx.x;
  if (tid == 0) {
    carry = 0;
    rowptr[0] = 0;
  }
  __syncthreads();
  for (int base = 0; base < n; base += 1024) {
    int i = base + tid;
    int v = (i < n) ? cursor[i] : 0;
    smem[tid] = v;
    __syncthreads();
#pragma unroll
    for (int off = 1; off < 1024; off <<= 1) {
      int t = (tid >= off) ? smem[tid - off] : 0;
      __syncthreads();
      smem[tid] += t;
      __syncthreads();
    }
    int inc = smem[tid];
    int c = carry;
    if (i < n) {
      rowptr[i + 1] = c + inc;
      cursor[i] = c + inc - v;  // exclusive
    }
    __syncthreads();
    if (tid == 1023) carry = c + smem[1023];
    __syncthreads();
  }
}
__global__ void scatter_kernel(const int* __restrict__ src,
                               const int* __restrict__ dst, int* cursor,
                               int* __restrict__ srcs, int E, int n) {
  int t = blockIdx.x * 256 + threadIdx.x;
  if (t < E) {
    int d = dst[t];
    int pos = atomicAdd(&cursor[d], 1);
    srcs[pos] = src[t];
  } else if (t < E + n) {
    int node = t - E;
    int pos = atomicAdd(&cursor[node], 1);
    srcs[pos] = node;  // self-loop
  }
}

// ---------------- per-dst-node softmax + aggregate + fused epilogue ----------
__global__ __launch_bounds__(256) void agg_kernel(
    const int* __restrict__ rowptr, const int* __restrict__ srcs,
    const float* __restrict__ H, const float* __restrict__ eS,
    const float* __restrict__ eD, const float* __restrict__ bias,
    const float* __restrict__ resid, const float* __restrict__ gamma,
    const float* __restrict__ beta, float* __restrict__ out, int n) {
  const int lane = threadIdx.x & 63;
  const int node = blockIdx.x * 4 + (threadIdx.x >> 6);
  if (node >= n) return;
  const int start = rowptr[node];
  const int end = rowptr[node + 1];
  const float4 edv = *(const float4*)(eD + (long)node * 4);
  const float ed0 = edv.x, ed1 = edv.y, ed2 = edv.z, ed3 = edv.w;

  // pass A: per-head max (lanes stride edges)
  float m0 = -1e30f, m1 = -1e30f, m2 = -1e30f, m3 = -1e30f;
  for (int i = start + lane; i < end; i += 64) {
    int s = srcs[i];
    float4 es = *(const float4*)(eS + (long)s * 4);
    float e;
    e = es.x + ed0; e = e > 0.f ? e : 0.2f * e; m0 = fmaxf(m0, e);
    e = es.y + ed1; e = e > 0.f ? e : 0.2f * e; m1 = fmaxf(m1, e);
    e = es.z + ed2; e = e > 0.f ? e : 0.2f * e; m2 = fmaxf(m2, e);
    e = es.w + ed3; e = e > 0.f ? e : 0.2f * e; m3 = fmaxf(m3, e);
  }
#pragma unroll
  for (int m = 32; m >= 1; m >>= 1) {
    m0 = fmaxf(m0, __shfl_xor(m0, m, 64));
    m1 = fmaxf(m1, __shfl_xor(m1, m, 64));
    m2 = fmaxf(m2, __shfl_xor(m2, m, 64));
    m3 = fmaxf(m3, __shfl_xor(m3, m, 64));
  }
  // pass B: per-head sum of exp(e - m)
  float s0 = 0.f, s1 = 0.f, s2 = 0.f, s3 = 0.f;
  for (int i = start + lane; i < end; i += 64) {
    int s = srcs[i];
    float4 es = *(const float4*)(eS + (long)s * 4);
    float e;
    e = es.x + ed0; e = e > 0.f ? e : 0.2f * e; s0 += __expf(e - m0);
    e = es.y + ed1; e = e > 0.f ? e : 0.2f * e; s1 += __expf(e - m1);
    e = es.z + ed2; e = e > 0.f ? e : 0.2f * e; s2 += __expf(e - m2);
    e = es.w + ed3; e = e > 0.f ? e : 0.2f * e; s3 += __expf(e - m3);
  }
  s0 = wave_sum(s0); s1 = wave_sum(s1); s2 = wave_sum(s2); s3 = wave_sum(s3);
  const float i0 = 1.f / (s0 + 1e-16f), i1 = 1.f / (s1 + 1e-16f);
  const float i2 = 1.f / (s2 + 1e-16f), i3 = 1.f / (s3 + 1e-16f);

  // pass C: serial over edges; 64 lanes = 64 channels, 4 heads each
  float a0 = 0.f, a1 = 0.f, a2 = 0.f, a3 = 0.f;
  for (int i = start; i < end; ++i) {
    int s = srcs[i];  // wave-uniform
    float4 es = *(const float4*)(eS + (long)s * 4);
    const float* hrow = H + (long)s * 256;
    float e, al;
    e = es.x + ed0; e = e > 0.f ? e : 0.2f * e; al = __expf(e - m0) * i0;
    a0 = fmaf(al, hrow[lane], a0);
    e = es.y + ed1; e = e > 0.f ? e : 0.2f * e; al = __expf(e - m1) * i1;
    a1 = fmaf(al, hrow[64 + lane], a1);
    e = es.z + ed2; e = e > 0.f ? e : 0.2f * e; al = __expf(e - m2) * i2;
    a2 = fmaf(al, hrow[128 + lane], a2);
    e = es.w + ed3; e = e > 0.f ? e : 0.2f * e; al = __expf(e - m3) * i3;
    a3 = fmaf(al, hrow[192 + lane], a3);
  }

  // epilogue: mean over heads + bias, ELU, +residual, LayerNorm
  float o = (a0 + a1 + a2 + a3) * 0.25f + bias[lane];
  o = o > 0.f ? o : (__expf(o) - 1.f);                 // ELU
  float v = o + resid[(long)node * 64 + lane];
  float mean = wave_sum(v) * (1.f / 64.f);
  float d = v - mean;
  float var = wave_sum(d * d) * (1.f / 64.f);
  float r = rsqrtf(var + 1e-5f);
  out[(long)node * 64 + lane] = d * r * gamma[lane] + beta[lane];
}

// ---------------------------------------------------------------------------
extern "C" void kernel_launch(void* const* d_in, const int* in_sizes, int n_in,
                              void* d_out, int out_size, void* d_ws,
                              size_t ws_size, hipStream_t stream) {
  const float* x    = (const float*)d_in[0];
  const int*   ei   = (const int*)d_in[1];
  const float* W_in = (const float*)d_in[2];
  const float* b_in = (const float*)d_in[3];
  const float* W1   = (const float*)d_in[4];
  const float* a1s  = (const float*)d_in[5];
  const float* a1d  = (const float*)d_in[6];
  const float* b1   = (const float*)d_in[7];
  const float* W2   = (const float*)d_in[8];
  const float* a2s  = (const float*)d_in[9];
  const float* a2d  = (const float*)d_in[10];
  const float* b2   = (const float*)d_in[11];
  const float* g1   = (const float*)d_in[12];
  const float* be1  = (const float*)d_in[13];
  const float* g2   = (const float*)d_in[14];
  const float* be2  = (const float*)d_in[15];
  const float* Wo   = (const float*)d_in[16];
  const float* bo   = (const float*)d_in[17];
  float* out = (float*)d_out;

  const int N = in_sizes[0] / 128;
  const int E = in_sizes[1] / 2;
  const int* src = ei;
  const int* dst = ei + E;

  float* ws  = (float*)d_ws;
  float* H   = ws;                   // N*256
  float* RES = H + (long)N * 256;    // N*64 (also HL2 output buffer)
  float* HL1 = RES + (long)N * 64;   // N*64
  float* eS  = HL1 + (long)N * 64;   // N*4
  float* eD  = eS + (long)N * 4;     // N*4
  int* rowptr = (int*)(eD + (long)N * 4);  // N+1
  int* cursor = rowptr + (N + 1);          // N (also deg)
  int* srcs   = cursor + N;                // E+N
  float* HL2 = RES;

  const dim3 blk(256);
  const int gemmGrid = (N + 31) / 32;
  const int nodeGrid = (N + 3) / 4;

  // CSR build (independent of GEMMs; same stream = ordered)
  initdeg_kernel<<<(N + 255) / 256, blk, 0, stream>>>(cursor, N);
  count_kernel<<<(E + 255) / 256, blk, 0, stream>>>(dst, cursor, E);
  scan_kernel<<<1, 1024, 0, stream>>>(cursor, rowptr, N);
  scatter_kernel<<<(E + N + 255) / 256, blk, 0, stream>>>(src, dst, cursor, srcs, E, N);

  // layer 1
  gemm_kernel<128, 256, false><<<gemmGrid, blk, 0, stream>>>(x, W1, nullptr, H, N);
  gemm_kernel<128, 64, true><<<gemmGrid, blk, 0, stream>>>(x, W_in, b_in, RES, N);
  attpre_kernel<<<nodeGrid, blk, 0, stream>>>(H, a1s, a1d, eS, eD, N);
  agg_kernel<<<nodeGrid, blk, 0, stream>>>(rowptr, srcs, H, eS, eD, b1, RES, g1,
                                           be1, HL1, N);
  // layer 2
  gemm_kernel<64, 256, false><<<gemmGrid, blk, 0, stream>>>(HL1, W2, nullptr, H, N);
  attpre_kernel<<<nodeGrid, blk, 0, stream>>>(H, a2s, a2d, eS, eD, N);
  agg_kernel<<<nodeGrid, blk, 0, stream>>>(rowptr, srcs, H, eS, eD, b2, HL1, g2,
                                           be2, HL2, N);
  // output projection
  gemm_kernel<64, 64, true><<<gemmGrid, blk, 0, stream>>>(HL2, Wo, bo, out, N);
}

// Round 2
// 531.692 us; speedup vs baseline: 1.1563x; 1.1563x over previous
//
#include <hip/hip_runtime.h>

// ---------------------------------------------------------------------------
// MultiViewGraphAttention: 2-layer GAT (H=4 heads, HID=64), fused epilogues.
//   CSR build: deg(atomic) -> wave-scan atomic segment assign -> scatter
//   Hb = pack_bf16(x@W1) in [node][ch][head] interleave; RES = x@W_in+b_in
//   attpre: eS/eD from Hb
//   agg: passA max(+store e) / passB exp(+store p)+sum / passC gather Hb
//        + mean-heads + bias + ELU + residual + LayerNorm (all in-wave)
//   layer 2 same; OUT = HL2@Wo + bo
// ---------------------------------------------------------------------------

__device__ __forceinline__ float wave_sum(float v) {
#pragma unroll
  for (int m = 32; m >= 1; m >>= 1) v += __shfl_xor(v, m, 64);
  return v;
}
__device__ __forceinline__ unsigned pack_bf16(float lo, float hi) {
  unsigned r;
  asm volatile("v_cvt_pk_bf16_f32 %0, %1, %2" : "=v"(r) : "v"(lo), "v"(hi));
  return r;  // lo in bits[15:0], hi in bits[31:16], RNE
}
__device__ __forceinline__ float bf_lo(unsigned u) { return __uint_as_float(u << 16); }
__device__ __forceinline__ float bf_hi(unsigned u) { return __uint_as_float(u & 0xffff0000u); }

// ---- GEMM J=256, epilogue packs to Hb[node][ch(lane)][head] bf16x4 (uint2)
template <int K>
__global__ __launch_bounds__(256) void gemm_pack_kernel(
    const float* __restrict__ A, const float* __restrict__ B,
    uint2* __restrict__ Hb, int nrows) {
  __shared__ float As[32 * K];
  const int row0 = blockIdx.x * 32;
  const int tid = threadIdx.x;
  int valid = nrows - row0;
  if (valid > 32) valid = 32;
  for (int idx = tid * 4; idx < 32 * K; idx += 256 * 4) {
    float4 v = make_float4(0.f, 0.f, 0.f, 0.f);
    if (idx < valid * K) v = *(const float4*)(A + (long)row0 * K + idx);
    *(float4*)(As + idx) = v;
  }
  __syncthreads();
  const int lane = tid & 63;
  const int wid = tid >> 6;
  float acc[8][4];
#pragma unroll
  for (int r = 0; r < 8; ++r)
#pragma unroll
    for (int v = 0; v < 4; ++v) acc[r][v] = 0.f;
  const float* Bp = B + lane;
#pragma unroll 4
  for (int k = 0; k < K; ++k) {
    float bv[4];
#pragma unroll
    for (int v = 0; v < 4; ++v) bv[v] = Bp[k * 256 + v * 64];
#pragma unroll
    for (int r = 0; r < 8; ++r) {
      float a = As[(wid * 8 + r) * K + k];
#pragma unroll
      for (int v = 0; v < 4; ++v) acc[r][v] = fmaf(a, bv[v], acc[r][v]);
    }
  }
#pragma unroll
  for (int r = 0; r < 8; ++r) {
    int row = row0 + wid * 8 + r;
    if (row < nrows) {
      uint2 pk;
      pk.x = pack_bf16(acc[r][0], acc[r][1]);  // heads 0,1 of channel `lane`
      pk.y = pack_bf16(acc[r][2], acc[r][3]);  // heads 2,3
      Hb[(long)row * 64 + lane] = pk;
    }
  }
}

// ---- GEMM J=64 fp32 (+bias): residual path and final projection
template <int K>
__global__ __launch_bounds__(256) void gemm64_kernel(
    const float* __restrict__ A, const float* __restrict__ B,
    const float* __restrict__ bias, float* __restrict__ C, int nrows) {
  __shared__ float As[32 * K];
  const int row0 = blockIdx.x * 32;
  const int tid = threadIdx.x;
  int valid = nrows - row0;
  if (valid > 32) valid = 32;
  for (int idx = tid * 4; idx < 32 * K; idx += 256 * 4) {
    float4 v = make_float4(0.f, 0.f, 0.f, 0.f);
    if (idx < valid * K) v = *(const float4*)(A + (long)row0 * K + idx);
    *(float4*)(As + idx) = v;
  }
  __syncthreads();
  const int lane = tid & 63;
  const int wid = tid >> 6;
  float acc[8];
#pragma unroll
  for (int r = 0; r < 8; ++r) acc[r] = 0.f;
#pragma unroll 4
  for (int k = 0; k < K; ++k) {
    float bv = B[k * 64 + lane];
#pragma unroll
    for (int r = 0; r < 8; ++r)
      acc[r] = fmaf(As[(wid * 8 + r) * K + k], bv, acc[r]);
  }
  const float bb = bias[lane];
#pragma unroll
  for (int r = 0; r < 8; ++r) {
    int row = row0 + wid * 8 + r;
    if (row < nrows) C[(long)row * 64 + lane] = acc[r] + bb;
  }
}

// ---- attention logits from packed Hb
__global__ __launch_bounds__(256) void attpre_kernel(
    const uint2* __restrict__ Hb, const float* __restrict__ a_src,
    const float* __restrict__ a_dst, float4* __restrict__ eS,
    float4* __restrict__ eD, int n) {
  const int lane = threadIdx.x & 63;
  const int node = blockIdx.x * 4 + (threadIdx.x >> 6);
  if (node >= n) return;
  uint2 hv = Hb[(long)node * 64 + lane];
  float h0 = bf_lo(hv.x), h1 = bf_hi(hv.x), h2 = bf_lo(hv.y), h3 = bf_hi(hv.y);
  float ps0 = h0 * a_src[lane],       ps1 = h1 * a_src[64 + lane];
  float ps2 = h2 * a_src[128 + lane], ps3 = h3 * a_src[192 + lane];
  float pd0 = h0 * a_dst[lane],       pd1 = h1 * a_dst[64 + lane];
  float pd2 = h2 * a_dst[128 + lane], pd3 = h3 * a_dst[192 + lane];
  ps0 = wave_sum(ps0); ps1 = wave_sum(ps1); ps2 = wave_sum(ps2); ps3 = wave_sum(ps3);
  pd0 = wave_sum(pd0); pd1 = wave_sum(pd1); pd2 = wave_sum(pd2); pd3 = wave_sum(pd3);
  if (lane == 0) {
    eS[node] = make_float4(ps0, ps1, ps2, ps3);
    eD[node] = make_float4(pd0, pd1, pd2, pd3);
  }
}

// ---- CSR build ----
__global__ void initdeg_kernel(int* deg, int* counter, int n) {
  int i = blockIdx.x * 256 + threadIdx.x;
  if (i < n) deg[i] = 1;  // self-loop
  if (i == 0) *counter = 0;
}
__global__ void count_kernel(const int* __restrict__ dst, int* deg, int E) {
  int e = blockIdx.x * 256 + threadIdx.x;
  if (e < E) atomicAdd(&deg[dst[e]], 1);
}
// segment assignment without a global scan: wave prefix + one atomic per wave
__global__ __launch_bounds__(256) void assign_kernel(
    const int* __restrict__ deg, int* __restrict__ rowstart,
    int* __restrict__ cursor, int* counter, int n) {
  const int i = blockIdx.x * 256 + threadIdx.x;
  const int lane = threadIdx.x & 63;
  int d = (i < n) ? deg[i] : 0;
  int incl = d;
#pragma unroll
  for (int off = 1; off < 64; off <<= 1) {
    int t = __shfl_up(incl, off, 64);
    if (lane >= off) incl += t;
  }
  int base = 0;
  if (lane == 63) base = atomicAdd(counter, incl);
  base = __shfl(base, 63, 64);
  int start = base + incl - d;
  if (i < n) {
    rowstart[i] = start;
    cursor[i] = start;
  }
}
__global__ void scatter_kernel(const int* __restrict__ src,
                               const int* __restrict__ dst, int* cursor,
                               int* __restrict__ srcs, int E, int n) {
  int t = blockIdx.x * 256 + threadIdx.x;
  if (t < E) {
    int pos = atomicAdd(&cursor[dst[t]], 1);
    srcs[pos] = src[t];
  } else if (t < E + n) {
    int node = t - E;
    int pos = atomicAdd(&cursor[node], 1);
    srcs[pos] = node;
  }
}

// ---- per-dst softmax + aggregate + mean-heads + bias + ELU + resid + LN ----
__global__ __launch_bounds__(256) void agg_kernel(
    const int* __restrict__ rowstart, const int* __restrict__ deg,
    const int* __restrict__ srcs, const uint2* __restrict__ Hb,
    const float4* __restrict__ eS, const float4* __restrict__ eD,
    float4* __restrict__ palpha, const float* __restrict__ bias,
    const float* __restrict__ resid, const float* __restrict__ gamma,
    const float* __restrict__ beta, float* __restrict__ out, int n) {
  const int lane = threadIdx.x & 63;
  const int node = blockIdx.x * 4 + (threadIdx.x >> 6);
  if (node >= n) return;
  const int start = rowstart[node];
  const int end = start + deg[node];
  const float4 edv = eD[node];

  // pass A: leaky-relu logits -> palpha, per-head max
  float m0 = -1e30f, m1 = -1e30f, m2 = -1e30f, m3 = -1e30f;
  for (int i = start + lane; i < end; i += 64) {
    float4 es = eS[srcs[i]];
    float e0 = es.x + edv.x; e0 = e0 > 0.f ? e0 : 0.2f * e0;
    float e1 = es.y + edv.y; e1 = e1 > 0.f ? e1 : 0.2f * e1;
    float e2 = es.z + edv.z; e2 = e2 > 0.f ? e2 : 0.2f * e2;
    float e3 = es.w + edv.w; e3 = e3 > 0.f ? e3 : 0.2f * e3;
    palpha[i] = make_float4(e0, e1, e2, e3);
    m0 = fmaxf(m0, e0); m1 = fmaxf(m1, e1);
    m2 = fmaxf(m2, e2); m3 = fmaxf(m3, e3);
  }
#pragma unroll
  for (int m = 32; m >= 1; m >>= 1) {
    m0 = fmaxf(m0, __shfl_xor(m0, m, 64));
    m1 = fmaxf(m1, __shfl_xor(m1, m, 64));
    m2 = fmaxf(m2, __shfl_xor(m2, m, 64));
    m3 = fmaxf(m3, __shfl_xor(m3, m, 64));
  }
  // pass B: p = exp(e-m) -> palpha, per-head sum
  float s0 = 0.f, s1 = 0.f, s2 = 0.f, s3 = 0.f;
  for (int i = start + lane; i < end; i += 64) {
    float4 e = palpha[i];
    float p0 = __expf(e.x - m0), p1 = __expf(e.y - m1);
    float p2 = __expf(e.z - m2), p3 = __expf(e.w - m3);
    palpha[i] = make_float4(p0, p1, p2, p3);
    s0 += p0; s1 += p1; s2 += p2; s3 += p3;
  }
  s0 = wave_sum(s0); s1 = wave_sum(s1); s2 = wave_sum(s2); s3 = wave_sum(s3);
  const float i0 = 1.f / (s0 + 1e-16f), i1 = 1.f / (s1 + 1e-16f);
  const float i2 = 1.f / (s2 + 1e-16f), i3 = 1.f / (s3 + 1e-16f);

  // pass C: serial edges; lane = channel, 4 heads packed per lane (uint2)
  float a0 = 0.f, a1 = 0.f, a2 = 0.f, a3 = 0.f;
  int sA = srcs[start];
  uint2 hA = Hb[(long)sA * 64 + lane];
  for (int i = start; i < end; ++i) {
    uint2 h = hA;
    if (i + 1 < end) {
      int sB = srcs[i + 1];
      hA = Hb[(long)sB * 64 + lane];
    }
    float4 p = palpha[i];  // wave-uniform
    a0 = fmaf(p.x * i0, bf_lo(h.x), a0);
    a1 = fmaf(p.y * i1, bf_hi(h.x), a1);
    a2 = fmaf(p.z * i2, bf_lo(h.y), a2);
    a3 = fmaf(p.w * i3, bf_hi(h.y), a3);
  }

  // epilogue: mean heads + bias, ELU, +residual, LayerNorm
  float o = (a0 + a1 + a2 + a3) * 0.25f + bias[lane];
  o = o > 0.f ? o : (__expf(o) - 1.f);
  float v = o + resid[(long)node * 64 + lane];
  float mean = wave_sum(v) * (1.f / 64.f);
  float d = v - mean;
  float var = wave_sum(d * d) * (1.f / 64.f);
  float r = rsqrtf(var + 1e-5f);
  out[(long)node * 64 + lane] = d * r * gamma[lane] + beta[lane];
}

// ---------------------------------------------------------------------------
extern "C" void kernel_launch(void* const* d_in, const int* in_sizes, int n_in,
                              void* d_out, int out_size, void* d_ws,
                              size_t ws_size, hipStream_t stream) {
  const float* x    = (const float*)d_in[0];
  const int*   ei   = (const int*)d_in[1];
  const float* W_in = (const float*)d_in[2];
  const float* b_in = (const float*)d_in[3];
  const float* W1   = (const float*)d_in[4];
  const float* a1s  = (const float*)d_in[5];
  const float* a1d  = (const float*)d_in[6];
  const float* b1   = (const float*)d_in[7];
  const float* W2   = (const float*)d_in[8];
  const float* a2s  = (const float*)d_in[9];
  const float* a2d  = (const float*)d_in[10];
  const float* b2   = (const float*)d_in[11];
  const float* g1   = (const float*)d_in[12];
  const float* be1  = (const float*)d_in[13];
  const float* g2   = (const float*)d_in[14];
  const float* be2  = (const float*)d_in[15];
  const float* Wo   = (const float*)d_in[16];
  const float* bo   = (const float*)d_in[17];
  float* out = (float*)d_out;

  const int N = in_sizes[0] / 128;
  const int E = in_sizes[1] / 2;
  const int* src = ei;
  const int* dst = ei + E;

  float* ws = (float*)d_ws;
  uint2* Hb   = (uint2*)ws;                 // N*64 uint2 (= N*128 floats)
  float* HL1  = ws + (long)N * 128;         // N*64
  float* RES  = HL1 + (long)N * 64;         // N*64 (reused as HL2)
  float4* eS  = (float4*)(RES + (long)N * 64);   // N
  float4* eD  = eS + N;                          // N
  float4* palpha = eD + N;                       // E+N
  int* deg      = (int*)(palpha + (long)(E + N));
  int* rowstart = deg + N;
  int* cursor   = rowstart + N;
  int* counter  = cursor + N;
  int* srcs     = counter + 1;              // E+N
  float* HL2 = RES;

  const dim3 blk(256);
  const int gemmGrid = (N + 31) / 32;
  const int nodeGrid = (N + 3) / 4;

  // CSR build
  initdeg_kernel<<<(N + 255) / 256, blk, 0, stream>>>(deg, counter, N);
  count_kernel<<<(E + 255) / 256, blk, 0, stream>>>(dst, deg, E);
  assign_kernel<<<(N + 255) / 256, blk, 0, stream>>>(deg, rowstart, cursor, counter, N);
  scatter_kernel<<<(E + N + 255) / 256, blk, 0, stream>>>(src, dst, cursor, srcs, E, N);

  // layer 1
  gemm_pack_kernel<128><<<gemmGrid, blk, 0, stream>>>(x, W1, Hb, N);
  gemm64_kernel<128><<<gemmGrid, blk, 0, stream>>>(x, W_in, b_in, RES, N);
  attpre_kernel<<<nodeGrid, blk, 0, stream>>>(Hb, a1s, a1d, eS, eD, N);
  agg_kernel<<<nodeGrid, blk, 0, stream>>>(rowstart, deg, srcs, Hb, eS, eD,
                                           palpha, b1, RES, g1, be1, HL1, N);
  // layer 2
  gemm_pack_kernel<64><<<gemmGrid, blk, 0, stream>>>(HL1, W2, Hb, N);
  attpre_kernel<<<nodeGrid, blk, 0, stream>>>(Hb, a2s, a2d, eS, eD, N);
  agg_kernel<<<nodeGrid, blk, 0, stream>>>(rowstart, deg, srcs, Hb, eS, eD,
                                           palpha, b2, HL1, g2, be2, HL2, N);
  // output projection
  gemm64_kernel<64><<<gemmGrid, blk, 0, stream>>>(HL2, Wo, bo, out, N);
}

// Round 3
// 523.929 us; speedup vs baseline: 1.1734x; 1.0148x over previous
//
#include <hip/hip_runtime.h>

// ---------------------------------------------------------------------------
// MultiViewGraphAttention: 2-layer GAT (H=4 heads, HID=64), fused epilogues.
//   CSR: memset deg -> count(atomic) -> assign(wave-scan+atomic) -> scatter
//   gemm_fused<128,true>: Hb=pack_bf16(x@W1) [node][ch][head], eS/eD logits
//                         (fp32 acc), RES=x@W_in+b_in  -- one A-tile pass
//   agg: softmax in registers (deg<=64 fast path), 4-deep pipelined gather,
//        + mean-heads + bias + ELU + residual + LayerNorm
//   gemm_fused<64,false>: layer 2; agg; OUT = HL2@Wo + bo
// ---------------------------------------------------------------------------

__device__ __forceinline__ float wave_sum(float v) {
#pragma unroll
  for (int m = 32; m >= 1; m >>= 1) v += __shfl_xor(v, m, 64);
  return v;
}
__device__ __forceinline__ float wave_max(float v) {
#pragma unroll
  for (int m = 32; m >= 1; m >>= 1) v = fmaxf(v, __shfl_xor(v, m, 64));
  return v;
}
__device__ __forceinline__ unsigned pack_bf16(float lo, float hi) {
  unsigned r;
  asm volatile("v_cvt_pk_bf16_f32 %0, %1, %2" : "=v"(r) : "v"(lo), "v"(hi));
  return r;
}
__device__ __forceinline__ float bf_lo(unsigned u) { return __uint_as_float(u << 16); }
__device__ __forceinline__ float bf_hi(unsigned u) { return __uint_as_float(u & 0xffff0000u); }
__device__ __forceinline__ float lrelu(float e) { return e > 0.f ? e : 0.2f * e; }

// ---- fused: C=A@B (J=256) -> pack Hb + attention logits; optional RES=A@B2+b2
template <int K, bool WITH_RES>
__global__ __launch_bounds__(256) void gemm_fused_kernel(
    const float* __restrict__ A, const float* __restrict__ B,
    const float* __restrict__ a_src, const float* __restrict__ a_dst,
    const float* __restrict__ B2, const float* __restrict__ bias2,
    uint2* __restrict__ Hb, float4* __restrict__ eS, float4* __restrict__ eD,
    float* __restrict__ RES, int nrows) {
  __shared__ float As[32 * K];
  const int row0 = blockIdx.x * 32;
  const int tid = threadIdx.x;
  int valid = nrows - row0;
  if (valid > 32) valid = 32;
  for (int idx = tid * 4; idx < 32 * K; idx += 256 * 4) {
    float4 v = make_float4(0.f, 0.f, 0.f, 0.f);
    if (idx < valid * K) v = *(const float4*)(A + (long)row0 * K + idx);
    *(float4*)(As + idx) = v;
  }
  __syncthreads();
  const int lane = tid & 63;
  const int wid = tid >> 6;
  float acc[8][4];
  float acc2[8];
#pragma unroll
  for (int r = 0; r < 8; ++r) {
    acc2[r] = 0.f;
#pragma unroll
    for (int v = 0; v < 4; ++v) acc[r][v] = 0.f;
  }
  const float* Bp = B + lane;
#pragma unroll 4
  for (int k = 0; k < K; ++k) {
    float bv[4];
#pragma unroll
    for (int v = 0; v < 4; ++v) bv[v] = Bp[k * 256 + v * 64];
    float bv2 = WITH_RES ? B2[k * 64 + lane] : 0.f;
#pragma unroll
    for (int r = 0; r < 8; ++r) {
      float a = As[(wid * 8 + r) * K + k];
#pragma unroll
      for (int v = 0; v < 4; ++v) acc[r][v] = fmaf(a, bv[v], acc[r][v]);
      if (WITH_RES) acc2[r] = fmaf(a, bv2, acc2[r]);
    }
  }
  float asr[4], adr[4];
#pragma unroll
  for (int v = 0; v < 4; ++v) {
    asr[v] = a_src[v * 64 + lane];
    adr[v] = a_dst[v * 64 + lane];
  }
  const float bb2 = WITH_RES ? bias2[lane] : 0.f;
#pragma unroll
  for (int r = 0; r < 8; ++r) {
    int row = row0 + wid * 8 + r;
    float ps0 = wave_sum(acc[r][0] * asr[0]);
    float ps1 = wave_sum(acc[r][1] * asr[1]);
    float ps2 = wave_sum(acc[r][2] * asr[2]);
    float ps3 = wave_sum(acc[r][3] * asr[3]);
    float pd0 = wave_sum(acc[r][0] * adr[0]);
    float pd1 = wave_sum(acc[r][1] * adr[1]);
    float pd2 = wave_sum(acc[r][2] * adr[2]);
    float pd3 = wave_sum(acc[r][3] * adr[3]);
    if (row < nrows) {
      uint2 pk;
      pk.x = pack_bf16(acc[r][0], acc[r][1]);
      pk.y = pack_bf16(acc[r][2], acc[r][3]);
      Hb[(long)row * 64 + lane] = pk;
      if (WITH_RES) RES[(long)row * 64 + lane] = acc2[r] + bb2;
      if (lane == 0) {
        eS[row] = make_float4(ps0, ps1, ps2, ps3);
        eD[row] = make_float4(pd0, pd1, pd2, pd3);
      }
    }
  }
}

// ---- GEMM J=64 fp32 (+bias): final projection
template <int K>
__global__ __launch_bounds__(256) void gemm64_kernel(
    const float* __restrict__ A, const float* __restrict__ B,
    const float* __restrict__ bias, float* __restrict__ C, int nrows) {
  __shared__ float As[32 * K];
  const int row0 = blockIdx.x * 32;
  const int tid = threadIdx.x;
  int valid = nrows - row0;
  if (valid > 32) valid = 32;
  for (int idx = tid * 4; idx < 32 * K; idx += 256 * 4) {
    float4 v = make_float4(0.f, 0.f, 0.f, 0.f);
    if (idx < valid * K) v = *(const float4*)(A + (long)row0 * K + idx);
    *(float4*)(As + idx) = v;
  }
  __syncthreads();
  const int lane = tid & 63;
  const int wid = tid >> 6;
  float acc[8];
#pragma unroll
  for (int r = 0; r < 8; ++r) acc[r] = 0.f;
#pragma unroll 4
  for (int k = 0; k < K; ++k) {
    float bv = B[k * 64 + lane];
#pragma unroll
    for (int r = 0; r < 8; ++r)
      acc[r] = fmaf(As[(wid * 8 + r) * K + k], bv, acc[r]);
  }
  const float bb = bias[lane];
#pragma unroll
  for (int r = 0; r < 8; ++r) {
    int row = row0 + wid * 8 + r;
    if (row < nrows) C[(long)row * 64 + lane] = acc[r] + bb;
  }
}

// ---- CSR build (deg excludes self-loop; +1 applied at use sites) ----
__global__ void count_kernel(const int* __restrict__ dst, int* deg, int E) {
  int e = blockIdx.x * 256 + threadIdx.x;
  if (e < E) atomicAdd(&deg[dst[e]], 1);
}
__global__ __launch_bounds__(256) void assign_kernel(
    const int* __restrict__ deg, int* __restrict__ rowstart,
    int* __restrict__ cursor, int* counter, int n) {
  const int i = blockIdx.x * 256 + threadIdx.x;
  const int lane = threadIdx.x & 63;
  int d = (i < n) ? deg[i] + 1 : 0;
  int incl = d;
#pragma unroll
  for (int off = 1; off < 64; off <<= 1) {
    int t = __shfl_up(incl, off, 64);
    if (lane >= off) incl += t;
  }
  int base = 0;
  if (lane == 63) base = atomicAdd(counter, incl);
  base = __shfl(base, 63, 64);
  int start = base + incl - d;
  if (i < n) {
    rowstart[i] = start;
    cursor[i] = start;
  }
}
__global__ void scatter_kernel(const int* __restrict__ src,
                               const int* __restrict__ dst, int* cursor,
                               int* __restrict__ srcs, int E, int n) {
  int t = blockIdx.x * 256 + threadIdx.x;
  if (t < E) {
    int pos = atomicAdd(&cursor[dst[t]], 1);
    srcs[pos] = src[t];
  } else if (t < E + n) {
    int node = t - E;
    int pos = atomicAdd(&cursor[node], 1);
    srcs[pos] = node;
  }
}

// ---- per-dst softmax + aggregate + mean-heads + bias + ELU + resid + LN ----
__global__ __launch_bounds__(256) void agg_kernel(
    const int* __restrict__ rowstart, const int* __restrict__ deg,
    const int* __restrict__ srcs, const uint2* __restrict__ Hb,
    const float4* __restrict__ eS, const float4* __restrict__ eD,
    const float* __restrict__ bias, const float* __restrict__ resid,
    const float* __restrict__ gamma, const float* __restrict__ beta,
    float* __restrict__ out, int n) {
  const int lane = threadIdx.x & 63;
  const int node = blockIdx.x * 4 + (threadIdx.x >> 6);
  if (node >= n) return;
  const int start = rowstart[node];
  const int cnt = deg[node] + 1;
  const int end = start + cnt;
  const float4 ed = eD[node];

  float m0, m1, m2, m3, s0, s1, s2, s3;
  if (cnt <= 64) {
    // softmax stats fully in registers: one edge per lane
    float e0 = -1e30f, e1 = -1e30f, e2 = -1e30f, e3 = -1e30f;
    if (lane < cnt) {
      float4 es = eS[srcs[start + lane]];
      e0 = lrelu(es.x + ed.x);
      e1 = lrelu(es.y + ed.y);
      e2 = lrelu(es.z + ed.z);
      e3 = lrelu(es.w + ed.w);
    }
    m0 = wave_max(e0); m1 = wave_max(e1);
    m2 = wave_max(e2); m3 = wave_max(e3);
    float p0 = lane < cnt ? __expf(e0 - m0) : 0.f;
    float p1 = lane < cnt ? __expf(e1 - m1) : 0.f;
    float p2 = lane < cnt ? __expf(e2 - m2) : 0.f;
    float p3 = lane < cnt ? __expf(e3 - m3) : 0.f;
    s0 = wave_sum(p0); s1 = wave_sum(p1);
    s2 = wave_sum(p2); s3 = wave_sum(p3);
  } else {
    float M0 = -1e30f, M1 = -1e30f, M2 = -1e30f, M3 = -1e30f;
    for (int i = start + lane; i < end; i += 64) {
      float4 es = eS[srcs[i]];
      M0 = fmaxf(M0, lrelu(es.x + ed.x));
      M1 = fmaxf(M1, lrelu(es.y + ed.y));
      M2 = fmaxf(M2, lrelu(es.z + ed.z));
      M3 = fmaxf(M3, lrelu(es.w + ed.w));
    }
    m0 = wave_max(M0); m1 = wave_max(M1);
    m2 = wave_max(M2); m3 = wave_max(M3);
    float S0 = 0.f, S1 = 0.f, S2 = 0.f, S3 = 0.f;
    for (int i = start + lane; i < end; i += 64) {
      float4 es = eS[srcs[i]];
      S0 += __expf(lrelu(es.x + ed.x) - m0);
      S1 += __expf(lrelu(es.y + ed.y) - m1);
      S2 += __expf(lrelu(es.z + ed.z) - m2);
      S3 += __expf(lrelu(es.w + ed.w) - m3);
    }
    s0 = wave_sum(S0); s1 = wave_sum(S1);
    s2 = wave_sum(S2); s3 = wave_sum(S3);
  }
  const float i0 = 1.f / (s0 + 1e-16f), i1 = 1.f / (s1 + 1e-16f);
  const float i2 = 1.f / (s2 + 1e-16f), i3 = 1.f / (s3 + 1e-16f);

  // pass C: 4-deep software-pipelined gather; lane = channel, heads packed
  float a0 = 0.f, a1 = 0.f, a2 = 0.f, a3 = 0.f;
  const int ng = cnt >> 2;
  uint2 hc[4];
  float4 ec[4];
  int base = start;
  if (ng) {
#pragma unroll
    for (int j = 0; j < 4; ++j) {
      int s = srcs[base + j];
      hc[j] = Hb[(long)s * 64 + lane];
      ec[j] = eS[s];
    }
  }
  for (int g = 0; g < ng; ++g) {
    uint2 hn[4];
    float4 en[4];
    const bool more = (g + 1 < ng);
    if (more) {
#pragma unroll
      for (int j = 0; j < 4; ++j) {
        int s = srcs[base + 4 + j];
        hn[j] = Hb[(long)s * 64 + lane];
        en[j] = eS[s];
      }
    }
#pragma unroll
    for (int j = 0; j < 4; ++j) {
      float al;
      al = __expf(lrelu(ec[j].x + ed.x) - m0) * i0;
      a0 = fmaf(al, bf_lo(hc[j].x), a0);
      al = __expf(lrelu(ec[j].y + ed.y) - m1) * i1;
      a1 = fmaf(al, bf_hi(hc[j].x), a1);
      al = __expf(lrelu(ec[j].z + ed.z) - m2) * i2;
      a2 = fmaf(al, bf_lo(hc[j].y), a2);
      al = __expf(lrelu(ec[j].w + ed.w) - m3) * i3;
      a3 = fmaf(al, bf_hi(hc[j].y), a3);
    }
    if (more) {
#pragma unroll
      for (int j = 0; j < 4; ++j) { hc[j] = hn[j]; ec[j] = en[j]; }
    }
    base += 4;
  }
  for (int i = start + (ng << 2); i < end; ++i) {
    int s = srcs[i];
    uint2 h = Hb[(long)s * 64 + lane];
    float4 es = eS[s];
    float al;
    al = __expf(lrelu(es.x + ed.x) - m0) * i0;
    a0 = fmaf(al, bf_lo(h.x), a0);
    al = __expf(lrelu(es.y + ed.y) - m1) * i1;
    a1 = fmaf(al, bf_hi(h.x), a1);
    al = __expf(lrelu(es.z + ed.z) - m2) * i2;
    a2 = fmaf(al, bf_lo(h.y), a2);
    al = __expf(lrelu(es.w + ed.w) - m3) * i3;
    a3 = fmaf(al, bf_hi(h.y), a3);
  }

  // epilogue: mean heads + bias, ELU, +residual, LayerNorm
  float o = (a0 + a1 + a2 + a3) * 0.25f + bias[lane];
  o = o > 0.f ? o : (__expf(o) - 1.f);
  float v = o + resid[(long)node * 64 + lane];
  float mean = wave_sum(v) * (1.f / 64.f);
  float d = v - mean;
  float var = wave_sum(d * d) * (1.f / 64.f);
  float r = rsqrtf(var + 1e-5f);
  out[(long)node * 64 + lane] = d * r * gamma[lane] + beta[lane];
}

// ---------------------------------------------------------------------------
extern "C" void kernel_launch(void* const* d_in, const int* in_sizes, int n_in,
                              void* d_out, int out_size, void* d_ws,
                              size_t ws_size, hipStream_t stream) {
  const float* x    = (const float*)d_in[0];
  const int*   ei   = (const int*)d_in[1];
  const float* W_in = (const float*)d_in[2];
  const float* b_in = (const float*)d_in[3];
  const float* W1   = (const float*)d_in[4];
  const float* a1s  = (const float*)d_in[5];
  const float* a1d  = (const float*)d_in[6];
  const float* b1   = (const float*)d_in[7];
  const float* W2   = (const float*)d_in[8];
  const float* a2s  = (const float*)d_in[9];
  const float* a2d  = (const float*)d_in[10];
  const float* b2   = (const float*)d_in[11];
  const float* g1   = (const float*)d_in[12];
  const float* be1  = (const float*)d_in[13];
  const float* g2   = (const float*)d_in[14];
  const float* be2  = (const float*)d_in[15];
  const float* Wo   = (const float*)d_in[16];
  const float* bo   = (const float*)d_in[17];
  float* out = (float*)d_out;

  const int N = in_sizes[0] / 128;
  const int E = in_sizes[1] / 2;
  const int* src = ei;
  const int* dst = ei + E;

  float* ws = (float*)d_ws;
  uint2* Hb   = (uint2*)ws;                      // N*64 uint2
  float* HL1  = ws + (long)N * 128;              // N*64
  float* RES  = HL1 + (long)N * 64;              // N*64 (reused as HL2)
  float4* eS  = (float4*)(RES + (long)N * 64);   // N
  float4* eD  = eS + N;                          // N
  int* deg      = (int*)(eD + N);                // N
  int* counter  = deg + N;                       // 1
  int* rowstart = counter + 1;                   // N
  int* cursor   = rowstart + N;                  // N
  int* srcs     = cursor + N;                    // E+N
  float* HL2 = RES;

  const dim3 blk(256);
  const int gemmGrid = (N + 31) / 32;
  const int nodeGrid = (N + 3) / 4;

  // CSR build
  hipMemsetAsync(deg, 0, (N + 1) * sizeof(int), stream);  // deg + counter
  count_kernel<<<(E + 255) / 256, blk, 0, stream>>>(dst, deg, E);
  assign_kernel<<<(N + 255) / 256, blk, 0, stream>>>(deg, rowstart, cursor, counter, N);
  scatter_kernel<<<(E + N + 255) / 256, blk, 0, stream>>>(src, dst, cursor, srcs, E, N);

  // layer 1 (fused: H1 pack + logits + residual GEMM)
  gemm_fused_kernel<128, true><<<gemmGrid, blk, 0, stream>>>(
      x, W1, a1s, a1d, W_in, b_in, Hb, eS, eD, RES, N);
  agg_kernel<<<nodeGrid, blk, 0, stream>>>(rowstart, deg, srcs, Hb, eS, eD, b1,
                                           RES, g1, be1, HL1, N);
  // layer 2
  gemm_fused_kernel<64, false><<<gemmGrid, blk, 0, stream>>>(
      HL1, W2, a2s, a2d, nullptr, nullptr, Hb, eS, eD, nullptr, N);
  agg_kernel<<<nodeGrid, blk, 0, stream>>>(rowstart, deg, srcs, Hb, eS, eD, b2,
                                           HL1, g2, be2, HL2, N);
  // output projection
  gemm64_kernel<64><<<gemmGrid, blk, 0, stream>>>(HL2, Wo, bo, out, N);
}

// Round 4
// 393.012 us; speedup vs baseline: 1.5643x; 1.3331x over previous
//
#include <hip/hip_runtime.h>

// ---------------------------------------------------------------------------
// MultiViewGraphAttention: 2-layer GAT (H=4 heads, HID=64), fused epilogues.
//   CSR: memset deg -> count(atomic) -> assign(wave-scan+atomic) -> scatter
//   gemm_fused<128,true>: Hb=pack_bf16(x@W1) [node][ch][head], eS/eD logits
//                         (fp32 acc), RES=x@W_in+b_in  -- one A-tile pass
//   agg fast path (deg<64): softmax stats in registers, one edge per lane;
//     pass C alphas/src via v_readlane broadcast (no recompute, no eS load),
//     4-deep pipelined Hb gather; + mean-heads+bias+ELU+residual+LayerNorm
//   gemm_fused<64,false>: layer 2; agg; OUT = HL2@Wo + bo
// ---------------------------------------------------------------------------

__device__ __forceinline__ float wave_sum(float v) {
#pragma unroll
  for (int m = 32; m >= 1; m >>= 1) v += __shfl_xor(v, m, 64);
  return v;
}
__device__ __forceinline__ float wave_max(float v) {
#pragma unroll
  for (int m = 32; m >= 1; m >>= 1) v = fmaxf(v, __shfl_xor(v, m, 64));
  return v;
}
__device__ __forceinline__ unsigned pack_bf16(float lo, float hi) {
  unsigned r;
  asm volatile("v_cvt_pk_bf16_f32 %0, %1, %2" : "=v"(r) : "v"(lo), "v"(hi));
  return r;
}
__device__ __forceinline__ float bf_lo(unsigned u) { return __uint_as_float(u << 16); }
__device__ __forceinline__ float bf_hi(unsigned u) { return __uint_as_float(u & 0xffff0000u); }
__device__ __forceinline__ float lrelu(float e) { return e > 0.f ? e : 0.2f * e; }
__device__ __forceinline__ float readlane_f(float v, int l) {
  return __uint_as_float(__builtin_amdgcn_readlane(__float_as_uint(v), l));
}

// ---- fused: C=A@B (J=256) -> pack Hb + attention logits; optional RES=A@B2+b2
template <int K, bool WITH_RES>
__global__ __launch_bounds__(256) void gemm_fused_kernel(
    const float* __restrict__ A, const float* __restrict__ B,
    const float* __restrict__ a_src, const float* __restrict__ a_dst,
    const float* __restrict__ B2, const float* __restrict__ bias2,
    uint2* __restrict__ Hb, float4* __restrict__ eS, float4* __restrict__ eD,
    float* __restrict__ RES, int nrows) {
  __shared__ float As[32 * K];
  const int row0 = blockIdx.x * 32;
  const int tid = threadIdx.x;
  int valid = nrows - row0;
  if (valid > 32) valid = 32;
  for (int idx = tid * 4; idx < 32 * K; idx += 256 * 4) {
    float4 v = make_float4(0.f, 0.f, 0.f, 0.f);
    if (idx < valid * K) v = *(const float4*)(A + (long)row0 * K + idx);
    *(float4*)(As + idx) = v;
  }
  __syncthreads();
  const int lane = tid & 63;
  const int wid = tid >> 6;
  float acc[8][4];
  float acc2[8];
#pragma unroll
  for (int r = 0; r < 8; ++r) {
    acc2[r] = 0.f;
#pragma unroll
    for (int v = 0; v < 4; ++v) acc[r][v] = 0.f;
  }
  const float* Bp = B + lane;
#pragma unroll 4
  for (int k = 0; k < K; ++k) {
    float bv[4];
#pragma unroll
    for (int v = 0; v < 4; ++v) bv[v] = Bp[k * 256 + v * 64];
    float bv2 = WITH_RES ? B2[k * 64 + lane] : 0.f;
#pragma unroll
    for (int r = 0; r < 8; ++r) {
      float a = As[(wid * 8 + r) * K + k];
#pragma unroll
      for (int v = 0; v < 4; ++v) acc[r][v] = fmaf(a, bv[v], acc[r][v]);
      if (WITH_RES) acc2[r] = fmaf(a, bv2, acc2[r]);
    }
  }
  float asr[4], adr[4];
#pragma unroll
  for (int v = 0; v < 4; ++v) {
    asr[v] = a_src[v * 64 + lane];
    adr[v] = a_dst[v * 64 + lane];
  }
  const float bb2 = WITH_RES ? bias2[lane] : 0.f;
#pragma unroll
  for (int r = 0; r < 8; ++r) {
    int row = row0 + wid * 8 + r;
    float ps0 = wave_sum(acc[r][0] * asr[0]);
    float ps1 = wave_sum(acc[r][1] * asr[1]);
    float ps2 = wave_sum(acc[r][2] * asr[2]);
    float ps3 = wave_sum(acc[r][3] * asr[3]);
    float pd0 = wave_sum(acc[r][0] * adr[0]);
    float pd1 = wave_sum(acc[r][1] * adr[1]);
    float pd2 = wave_sum(acc[r][2] * adr[2]);
    float pd3 = wave_sum(acc[r][3] * adr[3]);
    if (row < nrows) {
      uint2 pk;
      pk.x = pack_bf16(acc[r][0], acc[r][1]);
      pk.y = pack_bf16(acc[r][2], acc[r][3]);
      Hb[(long)row * 64 + lane] = pk;
      if (WITH_RES) RES[(long)row * 64 + lane] = acc2[r] + bb2;
      if (lane == 0) {
        eS[row] = make_float4(ps0, ps1, ps2, ps3);
        eD[row] = make_float4(pd0, pd1, pd2, pd3);
      }
    }
  }
}

// ---- GEMM J=64 fp32 (+bias): final projection
template <int K>
__global__ __launch_bounds__(256) void gemm64_kernel(
    const float* __restrict__ A, const float* __restrict__ B,
    const float* __restrict__ bias, float* __restrict__ C, int nrows) {
  __shared__ float As[32 * K];
  const int row0 = blockIdx.x * 32;
  const int tid = threadIdx.x;
  int valid = nrows - row0;
  if (valid > 32) valid = 32;
  for (int idx = tid * 4; idx < 32 * K; idx += 256 * 4) {
    float4 v = make_float4(0.f, 0.f, 0.f, 0.f);
    if (idx < valid * K) v = *(const float4*)(A + (long)row0 * K + idx);
    *(float4*)(As + idx) = v;
  }
  __syncthreads();
  const int lane = tid & 63;
  const int wid = tid >> 6;
  float acc[8];
#pragma unroll
  for (int r = 0; r < 8; ++r) acc[r] = 0.f;
#pragma unroll 4
  for (int k = 0; k < K; ++k) {
    float bv = B[k * 64 + lane];
#pragma unroll
    for (int r = 0; r < 8; ++r)
      acc[r] = fmaf(As[(wid * 8 + r) * K + k], bv, acc[r]);
  }
  const float bb = bias[lane];
#pragma unroll
  for (int r = 0; r < 8; ++r) {
    int row = row0 + wid * 8 + r;
    if (row < nrows) C[(long)row * 64 + lane] = acc[r] + bb;
  }
}

// ---- CSR build (deg excludes self-loop; +1 applied at use sites) ----
__global__ void count_kernel(const int* __restrict__ dst, int* deg, int E) {
  int e = blockIdx.x * 256 + threadIdx.x;
  if (e < E) atomicAdd(&deg[dst[e]], 1);
}
__global__ __launch_bounds__(256) void assign_kernel(
    const int* __restrict__ deg, int* __restrict__ rowstart,
    int* __restrict__ cursor, int* counter, int n) {
  const int i = blockIdx.x * 256 + threadIdx.x;
  const int lane = threadIdx.x & 63;
  int d = (i < n) ? deg[i] + 1 : 0;
  int incl = d;
#pragma unroll
  for (int off = 1; off < 64; off <<= 1) {
    int t = __shfl_up(incl, off, 64);
    if (lane >= off) incl += t;
  }
  int base = 0;
  if (lane == 63) base = atomicAdd(counter, incl);
  base = __shfl(base, 63, 64);
  int start = base + incl - d;
  if (i < n) {
    rowstart[i] = start;
    cursor[i] = start;
  }
}
__global__ void scatter_kernel(const int* __restrict__ src,
                               const int* __restrict__ dst, int* cursor,
                               int* __restrict__ srcs, int E, int n) {
  int t = blockIdx.x * 256 + threadIdx.x;
  if (t < E) {
    int pos = atomicAdd(&cursor[dst[t]], 1);
    srcs[pos] = src[t];
  } else if (t < E + n) {
    int node = t - E;
    int pos = atomicAdd(&cursor[node], 1);
    srcs[pos] = node;
  }
}

// ---- per-dst softmax + aggregate + mean-heads + bias + ELU + resid + LN ----
__global__ __launch_bounds__(256) void agg_kernel(
    const int* __restrict__ rowstart, const int* __restrict__ deg,
    const int* __restrict__ srcs, const uint2* __restrict__ Hb,
    const float4* __restrict__ eS, const float4* __restrict__ eD,
    const float* __restrict__ bias, const float* __restrict__ resid,
    const float* __restrict__ gamma, const float* __restrict__ beta,
    float* __restrict__ out, int n) {
  const int lane = threadIdx.x & 63;
  const int node = blockIdx.x * 4 + (threadIdx.x >> 6);
  if (node >= n) return;
  const int start = rowstart[node];
  const int cnt = deg[node] + 1;
  const int end = start + cnt;
  const float4 ed = eD[node];

  float a0 = 0.f, a1 = 0.f, a2 = 0.f, a3 = 0.f;

  if (cnt <= 64) {
    // ---- softmax stats fully in registers: one edge per lane ----
    const int sj = srcs[start + min(lane, cnt - 1)];  // clamped: always valid
    const float4 es = eS[sj];
    const bool act = lane < cnt;
    float e0 = lrelu(es.x + ed.x), e1 = lrelu(es.y + ed.y);
    float e2 = lrelu(es.z + ed.z), e3 = lrelu(es.w + ed.w);
    float m0 = wave_max(act ? e0 : -1e30f), m1 = wave_max(act ? e1 : -1e30f);
    float m2 = wave_max(act ? e2 : -1e30f), m3 = wave_max(act ? e3 : -1e30f);
    float p0 = act ? __expf(e0 - m0) : 0.f;
    float p1 = act ? __expf(e1 - m1) : 0.f;
    float p2 = act ? __expf(e2 - m2) : 0.f;
    float p3 = act ? __expf(e3 - m3) : 0.f;
    float s0 = wave_sum(p0), s1 = wave_sum(p1);
    float s2 = wave_sum(p2), s3 = wave_sum(p3);
    // normalized alpha for edge `lane` lives in this lane's p0..p3
    p0 *= 1.f / (s0 + 1e-16f);
    p1 *= 1.f / (s1 + 1e-16f);
    p2 *= 1.f / (s2 + 1e-16f);
    p3 *= 1.f / (s3 + 1e-16f);

    // ---- pass C: readlane-broadcast alpha + src; only Hb loads touch memory
    const uint2* HbL = Hb + lane;
    const int cntUp = (cnt + 3) & ~3;  // zero-alpha padding, no guards
#define LOADJ(dstv, jj)                                   \
  {                                                       \
    int s_ = __builtin_amdgcn_readlane(sj, (jj));         \
    dstv = HbL[(long)s_ * 64];                            \
  }
#define CONSJ(hv, jj)                                     \
  {                                                       \
    float q0 = readlane_f(p0, (jj));                      \
    float q1 = readlane_f(p1, (jj));                      \
    float q2 = readlane_f(p2, (jj));                      \
    float q3 = readlane_f(p3, (jj));                      \
    a0 = fmaf(q0, bf_lo(hv.x), a0);                       \
    a1 = fmaf(q1, bf_hi(hv.x), a1);                       \
    a2 = fmaf(q2, bf_lo(hv.y), a2);                       \
    a3 = fmaf(q3, bf_hi(hv.y), a3);                       \
  }
    uint2 hA, hB, hC, hD;
    LOADJ(hA, 0) LOADJ(hB, 1) LOADJ(hC, 2) LOADJ(hD, 3)
    int j = 0;
    for (; j + 8 <= cntUp; j += 4) {
      uint2 nA, nB, nC, nD;
      LOADJ(nA, j + 4) LOADJ(nB, j + 5) LOADJ(nC, j + 6) LOADJ(nD, j + 7)
      CONSJ(hA, j) CONSJ(hB, j + 1) CONSJ(hC, j + 2) CONSJ(hD, j + 3)
      hA = nA; hB = nB; hC = nC; hD = nD;
    }
    CONSJ(hA, j) CONSJ(hB, j + 1) CONSJ(hC, j + 2) CONSJ(hD, j + 3)
#undef LOADJ
#undef CONSJ
  } else {
    // ---- rare slow path (deg >= 64): strided stats + serial gather ----
    float M0 = -1e30f, M1 = -1e30f, M2 = -1e30f, M3 = -1e30f;
    for (int i = start + lane; i < end; i += 64) {
      float4 es = eS[srcs[i]];
      M0 = fmaxf(M0, lrelu(es.x + ed.x));
      M1 = fmaxf(M1, lrelu(es.y + ed.y));
      M2 = fmaxf(M2, lrelu(es.z + ed.z));
      M3 = fmaxf(M3, lrelu(es.w + ed.w));
    }
    float m0 = wave_max(M0), m1 = wave_max(M1);
    float m2 = wave_max(M2), m3 = wave_max(M3);
    float S0 = 0.f, S1 = 0.f, S2 = 0.f, S3 = 0.f;
    for (int i = start + lane; i < end; i += 64) {
      float4 es = eS[srcs[i]];
      S0 += __expf(lrelu(es.x + ed.x) - m0);
      S1 += __expf(lrelu(es.y + ed.y) - m1);
      S2 += __expf(lrelu(es.z + ed.z) - m2);
      S3 += __expf(lrelu(es.w + ed.w) - m3);
    }
    float i0 = 1.f / (wave_sum(S0) + 1e-16f), i1 = 1.f / (wave_sum(S1) + 1e-16f);
    float i2 = 1.f / (wave_sum(S2) + 1e-16f), i3 = 1.f / (wave_sum(S3) + 1e-16f);
    for (int i = start; i < end; ++i) {
      int s = srcs[i];
      uint2 h = Hb[(long)s * 64 + lane];
      float4 es = eS[s];
      float al;
      al = __expf(lrelu(es.x + ed.x) - m0) * i0;
      a0 = fmaf(al, bf_lo(h.x), a0);
      al = __expf(lrelu(es.y + ed.y) - m1) * i1;
      a1 = fmaf(al, bf_hi(h.x), a1);
      al = __expf(lrelu(es.z + ed.z) - m2) * i2;
      a2 = fmaf(al, bf_lo(h.y), a2);
      al = __expf(lrelu(es.w + ed.w) - m3) * i3;
      a3 = fmaf(al, bf_hi(h.y), a3);
    }
  }

  // epilogue: mean heads + bias, ELU, +residual, LayerNorm
  float o = (a0 + a1 + a2 + a3) * 0.25f + bias[lane];
  o = o > 0.f ? o : (__expf(o) - 1.f);
  float v = o + resid[(long)node * 64 + lane];
  float mean = wave_sum(v) * (1.f / 64.f);
  float d = v - mean;
  float var = wave_sum(d * d) * (1.f / 64.f);
  float r = rsqrtf(var + 1e-5f);
  out[(long)node * 64 + lane] = d * r * gamma[lane] + beta[lane];
}

// ---------------------------------------------------------------------------
extern "C" void kernel_launch(void* const* d_in, const int* in_sizes, int n_in,
                              void* d_out, int out_size, void* d_ws,
                              size_t ws_size, hipStream_t stream) {
  const float* x    = (const float*)d_in[0];
  const int*   ei   = (const int*)d_in[1];
  const float* W_in = (const float*)d_in[2];
  const float* b_in = (const float*)d_in[3];
  const float* W1   = (const float*)d_in[4];
  const float* a1s  = (const float*)d_in[5];
  const float* a1d  = (const float*)d_in[6];
  const float* b1   = (const float*)d_in[7];
  const float* W2   = (const float*)d_in[8];
  const float* a2s  = (const float*)d_in[9];
  const float* a2d  = (const float*)d_in[10];
  const float* b2   = (const float*)d_in[11];
  const float* g1   = (const float*)d_in[12];
  const float* be1  = (const float*)d_in[13];
  const float* g2   = (const float*)d_in[14];
  const float* be2  = (const float*)d_in[15];
  const float* Wo   = (const float*)d_in[16];
  const float* bo   = (const float*)d_in[17];
  float* out = (float*)d_out;

  const int N = in_sizes[0] / 128;
  const int E = in_sizes[1] / 2;
  const int* src = ei;
  const int* dst = ei + E;

  float* ws = (float*)d_ws;
  uint2* Hb   = (uint2*)ws;                      // N*64 uint2
  float* HL1  = ws + (long)N * 128;              // N*64
  float* RES  = HL1 + (long)N * 64;              // N*64 (reused as HL2)
  float4* eS  = (float4*)(RES + (long)N * 64);   // N
  float4* eD  = eS + N;                          // N
  int* deg      = (int*)(eD + N);                // N
  int* counter  = deg + N;                       // 1
  int* rowstart = counter + 1;                   // N
  int* cursor   = rowstart + N;                  // N
  int* srcs     = cursor + N;                    // E+N
  float* HL2 = RES;

  const dim3 blk(256);
  const int gemmGrid = (N + 31) / 32;
  const int nodeGrid = (N + 3) / 4;

  // CSR build
  hipMemsetAsync(deg, 0, (N + 1) * sizeof(int), stream);  // deg + counter
  count_kernel<<<(E + 255) / 256, blk, 0, stream>>>(dst, deg, E);
  assign_kernel<<<(N + 255) / 256, blk, 0, stream>>>(deg, rowstart, cursor, counter, N);
  scatter_kernel<<<(E + N + 255) / 256, blk, 0, stream>>>(src, dst, cursor, srcs, E, N);

  // layer 1 (fused: H1 pack + logits + residual GEMM)
  gemm_fused_kernel<128, true><<<gemmGrid, blk, 0, stream>>>(
      x, W1, a1s, a1d, W_in, b_in, Hb, eS, eD, RES, N);
  agg_kernel<<<nodeGrid, blk, 0, stream>>>(rowstart, deg, srcs, Hb, eS, eD, b1,
                                           RES, g1, be1, HL1, N);
  // layer 2
  gemm_fused_kernel<64, false><<<gemmGrid, blk, 0, stream>>>(
      HL1, W2, a2s, a2d, nullptr, nullptr, Hb, eS, eD, nullptr, N);
  agg_kernel<<<nodeGrid, blk, 0, stream>>>(rowstart, deg, srcs, Hb, eS, eD, b2,
                                           HL1, g2, be2, HL2, N);
  // output projection
  gemm64_kernel<64><<<gemmGrid, blk, 0, stream>>>(HL2, Wo, bo, out, N);
}

// Round 5
// 314.037 us; speedup vs baseline: 1.9577x; 1.2515x over previous
//
#include <hip/hip_runtime.h>

// ---------------------------------------------------------------------------
// MultiViewGraphAttention: 2-layer GAT (H=4 heads, HID=64), MFMA bf16 GEMMs.
//   CSR: memset -> count(atomic) -> assign(wave-scan+atomic) -> scatter
//   Weight prep: Wcat = [W | W_res? | Wa_src | Wa_dst] fp32, then packed to
//     MFMA B-fragment bf16 layout (Wa[k][h] = sum_c W[k][h*64+c]*a[h][c],
//     einsum reassociation kills the logit epilogue entirely).
//   mfma_gemm<MODE>: A(bf16 rows) @ Bpk -> Hb[node][ch][head] bf16x4,
//     eS/eD scalars, RES fp32 (+bias) or final out (+bias).
//   agg: softmax in registers (deg<=64), readlane-broadcast pass C,
//     + mean-heads + bias + ELU + residual + LayerNorm; writes fp32 + bf16.
// ---------------------------------------------------------------------------

using short8 = __attribute__((ext_vector_type(8))) short;
using floatx4 = __attribute__((ext_vector_type(4))) float;

__device__ __forceinline__ float wave_sum(float v) {
#pragma unroll
  for (int m = 32; m >= 1; m >>= 1) v += __shfl_xor(v, m, 64);
  return v;
}
__device__ __forceinline__ float wave_max(float v) {
#pragma unroll
  for (int m = 32; m >= 1; m >>= 1) v = fmaxf(v, __shfl_xor(v, m, 64));
  return v;
}
__device__ __forceinline__ unsigned pack_bf16(float lo, float hi) {
  unsigned r;
  asm volatile("v_cvt_pk_bf16_f32 %0, %1, %2" : "=v"(r) : "v"(lo), "v"(hi));
  return r;
}
__device__ __forceinline__ float bf_lo(unsigned u) { return __uint_as_float(u << 16); }
__device__ __forceinline__ float bf_hi(unsigned u) { return __uint_as_float(u & 0xffff0000u); }
__device__ __forceinline__ float lrelu(float e) { return e > 0.f ? e : 0.2f * e; }
__device__ __forceinline__ float readlane_f(float v, int l) {
  return __uint_as_float(__builtin_amdgcn_readlane(__float_as_uint(v), l));
}

// ---- fp32 -> bf16 vector convert (4 elems/thread, grid-stride) ----
__global__ void f2bf_kernel(const float* __restrict__ src,
                            ushort* __restrict__ dst, int nquads) {
  for (long i = blockIdx.x * 256 + threadIdx.x; i < nquads;
       i += (long)gridDim.x * 256) {
    float4 v = ((const float4*)src)[i];
    uint2 o;
    o.x = pack_bf16(v.x, v.y);
    o.y = pack_bf16(v.z, v.w);
    ((uint2*)dst)[i] = o;
  }
}

// ---- Wcat fp32 build: [W(256) | Wres(64)? | Wa_src(4) | Wa_dst(4) | pad] ----
__global__ void build_wcat_kernel(const float* __restrict__ W,
                                  const float* __restrict__ Wres,
                                  const float* __restrict__ a_src,
                                  const float* __restrict__ a_dst,
                                  float* __restrict__ Wcat, int K, int Jp,
                                  int resBase, int waBase) {
  int idx = blockIdx.x * 256 + threadIdx.x;
  int k = idx / Jp, j = idx - k * Jp;
  if (k >= K) return;
  float v = 0.f;
  if (j < 256) {
    v = W[k * 256 + j];
  } else if (resBase >= 0 && j >= resBase && j < resBase + 64) {
    v = Wres[k * 64 + (j - resBase)];
  } else if (j >= waBase && j < waBase + 8) {
    int h = j - waBase;
    const float* a = (h < 4) ? a_src : a_dst;
    h &= 3;
    float s = 0.f;
    for (int c = 0; c < 64; ++c) s += W[k * 256 + h * 64 + c] * a[h * 64 + c];
    v = s;
  }
  Wcat[idx] = v;
}

// ---- pack row-major fp32 [K][J] -> MFMA B-frag bf16: [(kt*NT+nt)*64+lane][8]
__global__ __launch_bounds__(64) void pack_frag_kernel(
    const float* __restrict__ Wsrc, ushort* __restrict__ dst, int J, int NT) {
  const int tnt = blockIdx.x;           // kt*NT + nt
  const int kt = tnt / NT, nt = tnt - kt * NT;
  const int l = threadIdx.x, l15 = l & 15, lhi = l >> 4;
  const int kbase = kt * 32 + lhi * 8;
  const int col = nt * 16 + l15;
  uint4 o;
  o.x = pack_bf16(Wsrc[(kbase + 0) * J + col], Wsrc[(kbase + 1) * J + col]);
  o.y = pack_bf16(Wsrc[(kbase + 2) * J + col], Wsrc[(kbase + 3) * J + col]);
  o.z = pack_bf16(Wsrc[(kbase + 4) * J + col], Wsrc[(kbase + 5) * J + col]);
  o.w = pack_bf16(Wsrc[(kbase + 6) * J + col], Wsrc[(kbase + 7) * J + col]);
  *(uint4*)(dst + ((long)tnt * 64 + l) * 8) = o;
}

// ---- MFMA GEMM. MODE 1: Hb + RES(+bias) + eS/eD (NT=21)
//                 MODE 2: Hb + eS/eD (NT=17)
//                 MODE 3: fp32 out (+bias) (NT=4)
template <int KA, int KT, int NT, int MODE>
__global__ __launch_bounds__(256) void mfma_gemm_kernel(
    const ushort* __restrict__ Abf, const ushort* __restrict__ Bpk,
    const float* __restrict__ bias, uint2* __restrict__ Hb,
    float* __restrict__ eSs, float* __restrict__ eDs, float* __restrict__ RES,
    float* __restrict__ outp, int nrows) {
  const int lane = threadIdx.x & 63;
  const int wid = threadIdx.x >> 6;
  const int row0 = (blockIdx.x * 4 + wid) * 16;
  if (row0 >= nrows) return;
  const int l15 = lane & 15, lhi = lane >> 4;
  floatx4 acc[NT];
  const floatx4 zero = {0.f, 0.f, 0.f, 0.f};
#pragma unroll
  for (int nt = 0; nt < NT; ++nt) acc[nt] = zero;
  const ushort* arow = Abf + (long)(row0 + l15) * KA + lhi * 8;
#pragma unroll
  for (int kt = 0; kt < KT; ++kt) {
    short8 af = *(const short8*)(arow + kt * 32);
    const ushort* bp = Bpk + ((long)(kt * NT) * 64 + lane) * 8;
#pragma unroll
    for (int nt = 0; nt < NT; ++nt) {
      short8 bf = *(const short8*)(bp + (long)nt * 64 * 8);
      acc[nt] = __builtin_amdgcn_mfma_f32_16x16x32_bf16(af, bf, acc[nt], 0, 0, 0);
    }
  }
#pragma unroll
  for (int reg = 0; reg < 4; ++reg) {
    const int node = row0 + lhi * 4 + reg;
    if (node >= nrows) continue;
    if (MODE == 1 || MODE == 2) {
      // Hb[node][ch][head]: ch = nt*16+l15; heads live 4 n-tiles apart
#pragma unroll
      for (int nt = 0; nt < 4; ++nt) {
        uint2 pk;
        pk.x = pack_bf16(acc[nt][reg], acc[nt + 4][reg]);
        pk.y = pack_bf16(acc[nt + 8][reg], acc[nt + 12][reg]);
        Hb[(long)node * 64 + nt * 16 + l15] = pk;
      }
      if (MODE == 1) {
#pragma unroll
        for (int nt = 16; nt < 20; ++nt) {
          int col = (nt - 16) * 16 + l15;
          RES[(long)node * 64 + col] = acc[nt][reg] + bias[col];
        }
      }
      constexpr int ET = (MODE == 1) ? 20 : 16;
      float ev = acc[ET][reg];
      if (l15 < 4) eSs[node * 4 + l15] = ev;
      else if (l15 < 8) eDs[node * 4 + (l15 - 4)] = ev;
    } else {
#pragma unroll
      for (int nt = 0; nt < NT; ++nt) {
        int col = nt * 16 + l15;
        outp[(long)node * 64 + col] = acc[nt][reg] + bias[col];
      }
    }
  }
}

// ---- CSR build (deg excludes self-loop; +1 applied at use sites) ----
__global__ void count_kernel(const int* __restrict__ dst, int* deg, int E) {
  int e = blockIdx.x * 256 + threadIdx.x;
  if (e < E) atomicAdd(&deg[dst[e]], 1);
}
__global__ __launch_bounds__(256) void assign_kernel(
    const int* __restrict__ deg, int* __restrict__ rowstart,
    int* __restrict__ cursor, int* counter, int n) {
  const int i = blockIdx.x * 256 + threadIdx.x;
  const int lane = threadIdx.x & 63;
  int d = (i < n) ? deg[i] + 1 : 0;
  int incl = d;
#pragma unroll
  for (int off = 1; off < 64; off <<= 1) {
    int t = __shfl_up(incl, off, 64);
    if (lane >= off) incl += t;
  }
  int base = 0;
  if (lane == 63) base = atomicAdd(counter, incl);
  base = __shfl(base, 63, 64);
  int start = base + incl - d;
  if (i < n) {
    rowstart[i] = start;
    cursor[i] = start;
  }
}
__global__ void scatter_kernel(const int* __restrict__ src,
                               const int* __restrict__ dst, int* cursor,
                               int* __restrict__ srcs, int E, int n) {
  int t = blockIdx.x * 256 + threadIdx.x;
  if (t < E) {
    int pos = atomicAdd(&cursor[dst[t]], 1);
    srcs[pos] = src[t];
  } else if (t < E + n) {
    int node = t - E;
    int pos = atomicAdd(&cursor[node], 1);
    srcs[pos] = node;
  }
}

// ---- per-dst softmax + aggregate + mean-heads + bias + ELU + resid + LN ----
__global__ __launch_bounds__(256) void agg_kernel(
    const int* __restrict__ rowstart, const int* __restrict__ deg,
    const int* __restrict__ srcs, const uint2* __restrict__ Hb,
    const float4* __restrict__ eS, const float4* __restrict__ eD,
    const float* __restrict__ bias, const float* __restrict__ resid,
    const float* __restrict__ gamma, const float* __restrict__ beta,
    float* __restrict__ out, ushort* __restrict__ outbf, int n) {
  const int lane = threadIdx.x & 63;
  const int node = blockIdx.x * 4 + (threadIdx.x >> 6);
  if (node >= n) return;
  const int start = rowstart[node];
  const int cnt = deg[node] + 1;
  const int end = start + cnt;
  const float4 ed = eD[node];

  float a0 = 0.f, a1 = 0.f, a2 = 0.f, a3 = 0.f;

  if (cnt <= 64) {
    const int sj = srcs[start + min(lane, cnt - 1)];
    const float4 es = eS[sj];
    const bool act = lane < cnt;
    float e0 = lrelu(es.x + ed.x), e1 = lrelu(es.y + ed.y);
    float e2 = lrelu(es.z + ed.z), e3 = lrelu(es.w + ed.w);
    float m0 = wave_max(act ? e0 : -1e30f), m1 = wave_max(act ? e1 : -1e30f);
    float m2 = wave_max(act ? e2 : -1e30f), m3 = wave_max(act ? e3 : -1e30f);
    float p0 = act ? __expf(e0 - m0) : 0.f;
    float p1 = act ? __expf(e1 - m1) : 0.f;
    float p2 = act ? __expf(e2 - m2) : 0.f;
    float p3 = act ? __expf(e3 - m3) : 0.f;
    float s0 = wave_sum(p0), s1 = wave_sum(p1);
    float s2 = wave_sum(p2), s3 = wave_sum(p3);
    p0 *= 1.f / (s0 + 1e-16f);
    p1 *= 1.f / (s1 + 1e-16f);
    p2 *= 1.f / (s2 + 1e-16f);
    p3 *= 1.f / (s3 + 1e-16f);

    const uint2* HbL = Hb + lane;
    const int cntUp = (cnt + 3) & ~3;
#define LOADJ(dstv, jj)                                   \
  {                                                       \
    int s_ = __builtin_amdgcn_readlane(sj, (jj));         \
    dstv = HbL[(long)s_ * 64];                            \
  }
#define CONSJ(hv, jj)                                     \
  {                                                       \
    float q0 = readlane_f(p0, (jj));                      \
    float q1 = readlane_f(p1, (jj));                      \
    float q2 = readlane_f(p2, (jj));                      \
    float q3 = readlane_f(p3, (jj));                      \
    a0 = fmaf(q0, bf_lo(hv.x), a0);                       \
    a1 = fmaf(q1, bf_hi(hv.x), a1);                       \
    a2 = fmaf(q2, bf_lo(hv.y), a2);                       \
    a3 = fmaf(q3, bf_hi(hv.y), a3);                       \
  }
    uint2 hA, hB, hC, hD;
    LOADJ(hA, 0) LOADJ(hB, 1) LOADJ(hC, 2) LOADJ(hD, 3)
    int j = 0;
    for (; j + 8 <= cntUp; j += 4) {
      uint2 nA, nB, nC, nD;
      LOADJ(nA, j + 4) LOADJ(nB, j + 5) LOADJ(nC, j + 6) LOADJ(nD, j + 7)
      CONSJ(hA, j) CONSJ(hB, j + 1) CONSJ(hC, j + 2) CONSJ(hD, j + 3)
      hA = nA; hB = nB; hC = nC; hD = nD;
    }
    CONSJ(hA, j) CONSJ(hB, j + 1) CONSJ(hC, j + 2) CONSJ(hD, j + 3)
#undef LOADJ
#undef CONSJ
  } else {
    float M0 = -1e30f, M1 = -1e30f, M2 = -1e30f, M3 = -1e30f;
    for (int i = start + lane; i < end; i += 64) {
      float4 es = eS[srcs[i]];
      M0 = fmaxf(M0, lrelu(es.x + ed.x));
      M1 = fmaxf(M1, lrelu(es.y + ed.y));
      M2 = fmaxf(M2, lrelu(es.z + ed.z));
      M3 = fmaxf(M3, lrelu(es.w + ed.w));
    }
    float m0 = wave_max(M0), m1 = wave_max(M1);
    float m2 = wave_max(M2), m3 = wave_max(M3);
    float S0 = 0.f, S1 = 0.f, S2 = 0.f, S3 = 0.f;
    for (int i = start + lane; i < end; i += 64) {
      float4 es = eS[srcs[i]];
      S0 += __expf(lrelu(es.x + ed.x) - m0);
      S1 += __expf(lrelu(es.y + ed.y) - m1);
      S2 += __expf(lrelu(es.z + ed.z) - m2);
      S3 += __expf(lrelu(es.w + ed.w) - m3);
    }
    float i0 = 1.f / (wave_sum(S0) + 1e-16f), i1 = 1.f / (wave_sum(S1) + 1e-16f);
    float i2 = 1.f / (wave_sum(S2) + 1e-16f), i3 = 1.f / (wave_sum(S3) + 1e-16f);
    for (int i = start; i < end; ++i) {
      int s = srcs[i];
      uint2 h = Hb[(long)s * 64 + lane];
      float4 es = eS[s];
      float al;
      al = __expf(lrelu(es.x + ed.x) - m0) * i0;
      a0 = fmaf(al, bf_lo(h.x), a0);
      al = __expf(lrelu(es.y + ed.y) - m1) * i1;
      a1 = fmaf(al, bf_hi(h.x), a1);
      al = __expf(lrelu(es.z + ed.z) - m2) * i2;
      a2 = fmaf(al, bf_lo(h.y), a2);
      al = __expf(lrelu(es.w + ed.w) - m3) * i3;
      a3 = fmaf(al, bf_hi(h.y), a3);
    }
  }

  float o = (a0 + a1 + a2 + a3) * 0.25f + bias[lane];
  o = o > 0.f ? o : (__expf(o) - 1.f);
  float v = o + resid[(long)node * 64 + lane];
  float mean = wave_sum(v) * (1.f / 64.f);
  float d = v - mean;
  float var = wave_sum(d * d) * (1.f / 64.f);
  float r = rsqrtf(var + 1e-5f);
  float res = d * r * gamma[lane] + beta[lane];
  out[(long)node * 64 + lane] = res;
  outbf[(long)node * 64 + lane] = (ushort)pack_bf16(res, res);
}

// ---------------------------------------------------------------------------
extern "C" void kernel_launch(void* const* d_in, const int* in_sizes, int n_in,
                              void* d_out, int out_size, void* d_ws,
                              size_t ws_size, hipStream_t stream) {
  const float* x    = (const float*)d_in[0];
  const int*   ei   = (const int*)d_in[1];
  const float* W_in = (const float*)d_in[2];
  const float* b_in = (const float*)d_in[3];
  const float* W1   = (const float*)d_in[4];
  const float* a1s  = (const float*)d_in[5];
  const float* a1d  = (const float*)d_in[6];
  const float* b1   = (const float*)d_in[7];
  const float* W2   = (const float*)d_in[8];
  const float* a2s  = (const float*)d_in[9];
  const float* a2d  = (const float*)d_in[10];
  const float* b2   = (const float*)d_in[11];
  const float* g1   = (const float*)d_in[12];
  const float* be1  = (const float*)d_in[13];
  const float* g2   = (const float*)d_in[14];
  const float* be2  = (const float*)d_in[15];
  const float* Wo   = (const float*)d_in[16];
  const float* bo   = (const float*)d_in[17];
  float* out = (float*)d_out;

  const int N = in_sizes[0] / 128;
  const int E = in_sizes[1] / 2;
  const int* src = ei;
  const int* dst = ei + E;

  // ---- workspace layout (bytes) ----
  char* p = (char*)d_ws;
  ushort* x_bf = (ushort*)p;      p += (long)N * 128 * 2;   // 12.8 MB
  uint2* Hb    = (uint2*)p;       p += (long)N * 64 * 8;    // 25.6 MB
  float* RES   = (float*)p;       p += (long)N * 64 * 4;    // 12.8 MB (reused as agg2 fp32 out)
  float* HL1   = (float*)p;       p += (long)N * 64 * 4;    // 12.8 MB
  ushort* HLbf = (ushort*)p;      p += (long)N * 64 * 2;    // 6.4 MB (HL1bf then HL2bf)
  float* eSs   = (float*)p;       p += (long)N * 4 * 4;     // 0.8 MB
  float* eDs   = (float*)p;       p += (long)N * 4 * 4;     // 0.8 MB
  float* Wcat1 = (float*)p;       p += 128L * 336 * 4;
  float* Wcat2 = (float*)p;       p += 64L * 272 * 4;
  ushort* Bpk1 = (ushort*)p;      p += 4L * 21 * 64 * 8 * 2;
  ushort* Bpk2 = (ushort*)p;      p += 2L * 17 * 64 * 8 * 2;
  ushort* Bpk3 = (ushort*)p;      p += 2L * 4 * 64 * 8 * 2;
  int* deg     = (int*)p;         p += (long)N * 4;
  int* counter = (int*)p;         p += 16;
  int* rowstart= (int*)p;         p += (long)N * 4;
  int* cursor  = (int*)p;         p += (long)N * 4;
  int* srcs    = (int*)p;         p += (long)(E + N) * 4;

  const dim3 blk(256);
  const int nodeGrid = (N + 3) / 4;
  const int mfmaGrid = (N + 63) / 64;

  // CSR build
  hipMemsetAsync(deg, 0, ((char*)rowstart - (char*)deg), stream);
  count_kernel<<<(E + 255) / 256, blk, 0, stream>>>(dst, deg, E);
  assign_kernel<<<(N + 255) / 256, blk, 0, stream>>>(deg, rowstart, cursor, counter, N);
  scatter_kernel<<<(E + N + 255) / 256, blk, 0, stream>>>(src, dst, cursor, srcs, E, N);

  // weight prep: Wcat fp32 then B-fragment bf16 pack
  build_wcat_kernel<<<(128 * 336 + 255) / 256, blk, 0, stream>>>(
      W1, W_in, a1s, a1d, Wcat1, 128, 336, 256, 320);
  build_wcat_kernel<<<(64 * 272 + 255) / 256, blk, 0, stream>>>(
      W2, nullptr, a2s, a2d, Wcat2, 64, 272, -1, 256);
  pack_frag_kernel<<<4 * 21, 64, 0, stream>>>(Wcat1, Bpk1, 336, 21);
  pack_frag_kernel<<<2 * 17, 64, 0, stream>>>(Wcat2, Bpk2, 272, 17);
  pack_frag_kernel<<<2 * 4, 64, 0, stream>>>(Wo, Bpk3, 64, 4);

  // x -> bf16
  f2bf_kernel<<<2048, blk, 0, stream>>>(x, x_bf, N * 32);

  // layer 1: Hb + RES + logits
  mfma_gemm_kernel<128, 4, 21, 1><<<mfmaGrid, blk, 0, stream>>>(
      x_bf, Bpk1, b_in, Hb, eSs, eDs, RES, nullptr, N);
  agg_kernel<<<nodeGrid, blk, 0, stream>>>(rowstart, deg, srcs, Hb,
                                           (const float4*)eSs, (const float4*)eDs,
                                           b1, RES, g1, be1, HL1, HLbf, N);
  // layer 2: Hb + logits (A = HL1 bf16)
  mfma_gemm_kernel<64, 2, 17, 2><<<mfmaGrid, blk, 0, stream>>>(
      HLbf, Bpk2, b_in, Hb, eSs, eDs, nullptr, nullptr, N);
  agg_kernel<<<nodeGrid, blk, 0, stream>>>(rowstart, deg, srcs, Hb,
                                           (const float4*)eSs, (const float4*)eDs,
                                           b2, HL1, g2, be2, RES, HLbf, N);
  // output projection (A = HL2 bf16)
  mfma_gemm_kernel<64, 2, 4, 3><<<mfmaGrid, blk, 0, stream>>>(
      HLbf, Bpk3, bo, nullptr, nullptr, nullptr, nullptr, out, N);
}